// Round 12
// baseline (93.221 us; speedup 1.0000x reference)
//
#include <hip/hip_runtime.h>
#include <math.h>

#define NN   1024
#define DD   256
#define NCLS 10

#define IB   16                 // i-rows per block (4 waves x 4)
#define JC   64                 // j-cols per block
#define SUBJ 16                 // j-rows per LDS stage
#define NJC  (NN / JC)          // 16
#define NBLK ((NN / IB) * NJC)  // 64*16 = 1024

typedef float f32x2 __attribute__((ext_vector_type(2)));
typedef float f32x4 __attribute__((ext_vector_type(4)));

#define PK_FMA(d, a, b, c) \
    asm("v_pk_fma_f32 %0, %1, %2, %3" : "=v"(d) : "v"(a), "v"(b), "v"(c))

// counts -> reciprocal weight tables
__global__ __launch_bounds__(256) void count_kernel(const long long* __restrict__ tgt,
                                                    float* __restrict__ wtab) {
    __shared__ int c[NCLS];
    int tid = threadIdx.x;
    if (tid < NCLS) c[tid] = 0;
    __syncthreads();
    for (int k = tid; k < NN; k += 256) atomicAdd(&c[(int)tgt[k]], 1);
    __syncthreads();
    if (tid < NCLS) {
        wtab[tid]      = 1.0f / (float)c[tid];         // wp = 1/cnt
        wtab[16 + tid] = 1.0f / (float)(NN - c[tid]);  // wn = 1/(N-cnt)
    }
}

// Dense-ne + inline eq-correction.
// Per i: D = sum_{all j,d} relu(-t); eq-only: E1 = sum relu(t), E2 = sum relu(-t).
// val(i) = wp*E1 + wn*(D - E2). t' = -t via negated coefficients:
// t' = (V'*f + B')*f + A', A'=-(fs^2*iv+0.5l), B'=2*fs*iv, V'=-iv.
// relu(-t) = max(t',0) = rn;  relu(t) = rn - t'.
__global__ __launch_bounds__(256) void pair_kernel(
    const float* __restrict__ fm_s, const float* __restrict__ fm_t,
    const float* __restrict__ lv, const long long* __restrict__ tgt,
    const float* __restrict__ wtab, float* __restrict__ val)
{
    __shared__ float Fl[SUBJ][DD];   // 16 KB, lane-linear (conflict-free b128)
    __shared__ int   tjL[JC];

    const int bid  = blockIdx.x;
    const int i0   = (bid >> 4) * IB;
    const int jc   = bid & (NJC - 1);
    const int j0   = jc * JC;

    const int tid  = threadIdx.x;
    const int w    = tid >> 6;
    const int lane = tid & 63;

    const int* tgt32 = (const int*)tgt;   // int64 low words, values 0..9

    if (tid < JC) tjL[tid] = tgt32[(j0 + tid) * 2];

    // ---- prologue: per-wave 4 i-rows, this lane's d-quad, in registers ----
    f32x4 a[4], b[4], v[4];
    int   ti_s[4];
    float wp_r[4], wn_r[4];
#pragma unroll
    for (int r = 0; r < 4; ++r) {
        const int row = i0 + w * 4 + r;
        const int g   = row * DD + lane * 4;
        const f32x4 fs = *(const f32x4*)&fm_s[g];
        const f32x4 l  = *(const f32x4*)&lv[g];
#pragma unroll
        for (int e = 0; e < 4; ++e) {
            const float iv   = 0.5f * __expf(-l[e]);   // 1/(2e^l+1e-12), rel ~1e-6
            const float fsiv = fs[e] * iv;
            a[r][e] = -fmaf(fsiv, fs[e], 0.5f * l[e]);
            b[r][e] = 2.0f * fsiv;
            v[r][e] = -iv;
        }
        ti_s[r] = __builtin_amdgcn_readfirstlane(tgt32[row * 2]);
        wp_r[r] = wtab[ti_s[r]];
        wn_r[r] = wtab[16 + ti_s[r]];
    }

    float accD[4][4];
    float e1[4], e2[4];
#pragma unroll
    for (int r = 0; r < 4; ++r) {
        e1[r] = 0.f; e2[r] = 0.f;
#pragma unroll
        for (int e = 0; e < 4; ++e) accD[r][e] = 0.f;
    }

    // ---- main: stream all JC j-rows in SUBJ-row LDS stages ----
    for (int sub = 0; sub < JC / SUBJ; ++sub) {
        __syncthreads();   // previous stage consumed (also orders tjL on sub=0)
#pragma unroll
        for (int p = 0; p < SUBJ / 4; ++p) {
            const int r = w * 4 + p;   // wave w stages rows 4w..4w+3
            *(f32x4*)&Fl[r][lane * 4] =
                *(const f32x4*)&fm_t[(j0 + sub * SUBJ + r) * DD + lane * 4];
        }
        __syncthreads();

#pragma unroll
        for (int jj = 0; jj < SUBJ; ++jj) {
            const f32x4 f  = *(const f32x4*)&Fl[jj][lane * 4];
            const int   tj = __builtin_amdgcn_readfirstlane(tjL[sub * SUBJ + jj]);
#pragma unroll
            for (int r = 0; r < 4; ++r) {
                f32x2 u0, u1, t0, t1;
                PK_FMA(u0, v[r].lo, f.lo, b[r].lo);
                PK_FMA(u1, v[r].hi, f.hi, b[r].hi);
                PK_FMA(t0, u0, f.lo, a[r].lo);
                PK_FMA(t1, u1, f.hi, a[r].hi);
                const float r0 = fmaxf(t0.x, 0.f);
                const float r1 = fmaxf(t0.y, 0.f);
                const float r2 = fmaxf(t1.x, 0.f);
                const float r3 = fmaxf(t1.y, 0.f);
                accD[r][0] += r0; accD[r][1] += r1;
                accD[r][2] += r2; accD[r][3] += r3;
                if (tj == ti_s[r]) {   // wave-uniform (s_cmp + s_cbranch)
                    e2[r] += (r0 + r1) + (r2 + r3);
                    e1[r] += ((r0 - t0.x) + (r1 - t0.y)) + ((r2 - t1.x) + (r3 - t1.y));
                }
            }
        }
    }

    // ---- reduce: per i-row, 64-lane shuffle tree; lane 0 writes weighted val ----
#pragma unroll
    for (int r = 0; r < 4; ++r) {
        float hD = (accD[r][0] + accD[r][1]) + (accD[r][2] + accD[r][3]);
        float h1 = e1[r];
        float h2 = e2[r];
#pragma unroll
        for (int off = 32; off > 0; off >>= 1) {
            hD += __shfl_down(hD, off);
            h1 += __shfl_down(h1, off);
            h2 += __shfl_down(h2, off);
        }
        if (lane == 0)
            val[(i0 + w * 4 + r) * NJC + jc] = wp_r[r] * h1 + wn_r[r] * (hD - h2);
    }
}

__global__ __launch_bounds__(256) void finalize_kernel(const float* __restrict__ val,
                                                       float* __restrict__ out) {
    __shared__ float red[256];
    const int tid = threadIdx.x;
    float s = 0.f;
#pragma unroll
    for (int k = 0; k < (NN * NJC) / 256; ++k) s += val[tid + k * 256];
    red[tid] = s;
    __syncthreads();
    for (int st = 128; st > 0; st >>= 1) {
        if (tid < st) red[tid] += red[tid + st];
        __syncthreads();
    }
    if (tid == 0) out[0] = red[0] * (1.0f / (float)NN);
}

extern "C" void kernel_launch(void* const* d_in, const int* in_sizes, int n_in,
                              void* d_out, int out_size, void* d_ws, size_t ws_size,
                              hipStream_t stream) {
    const float* fm_s    = (const float*)d_in[0];
    const float* fm_t    = (const float*)d_in[1];
    const float* lv      = (const float*)d_in[2];
    const long long* tgt = (const long long*)d_in[3];
    // fusion_true (d_in[4]) == 0 path implemented

    float* wtab = (float*)d_ws;                     // 32 floats
    float* val  = (float*)((char*)d_ws + 256);      // [1024][16] floats = 64 KB

    hipLaunchKernelGGL(count_kernel, dim3(1), dim3(256), 0, stream, tgt, wtab);
    hipLaunchKernelGGL(pair_kernel, dim3(NBLK), dim3(256), 0, stream,
                       fm_s, fm_t, lv, tgt, wtab, val);
    hipLaunchKernelGGL(finalize_kernel, dim3(1), dim3(256), 0, stream,
                       val, (float*)d_out);
}